// Round 6
// baseline (750.013 us; speedup 1.0000x reference)
//
#include <hip/hip_runtime.h>
#include <cstdint>
#include <cstddef>

typedef __bf16 bf16x8 __attribute__((ext_vector_type(8)));
typedef __bf16 bf16x4 __attribute__((ext_vector_type(4)));
typedef float fx4 __attribute__((ext_vector_type(4)));

static constexpr int T = 2048;
static constexpr int C = 4096;
static constexpr int H = 32;
static constexpr int HS = 128;
static constexpr int QKV_N = 12288; // 3*C

#define MFMA16(a, b, c) __builtin_amdgcn_mfma_f32_16x16x32_bf16((a), (b), (c), 0, 0, 0)

// async global->LDS, 16B per lane. LDS dest = wave-uniform base + lane*16 (m97/m104).
__device__ __forceinline__ void async_cp16(const void* g, void* l) {
  __builtin_amdgcn_global_load_lds((const __attribute__((address_space(1))) unsigned int*)g,
                                   (__attribute__((address_space(3))) unsigned int*)l,
                                   16, 0, 0);
}

// ---------------------------------------------------------------- fused fp32 -> bf16 (x, W_attn, W_proj)
// Round-6: ONE grid-strided kernel (2048 blocks), 8 floats/thread: 32B loads +
// 16B stores per lane. Replaces three 1-float4/thread kernels (49k tiny blocks,
// 8B stores) — suspected hidden-time sink; this is also the diagnostic.
__global__ __launch_bounds__(256) void cvt_all(const float* __restrict__ x,
                                               const float* __restrict__ Wa,
                                               const float* __restrict__ Wp,
                                               __bf16* __restrict__ xb,
                                               __bf16* __restrict__ Wab,
                                               __bf16* __restrict__ Wpb) {
  const int stride = gridDim.x * 256;
  const int tid0 = blockIdx.x * 256 + threadIdx.x;
  auto conv = [&](const float* __restrict__ in, __bf16* __restrict__ out, int n8) {
    for (int i = tid0; i < n8; i += stride) {
      float4 a = ((const float4*)in)[2 * i];
      float4 b = ((const float4*)in)[2 * i + 1];
      bf16x8 o;
      o[0] = (__bf16)a.x; o[1] = (__bf16)a.y; o[2] = (__bf16)a.z; o[3] = (__bf16)a.w;
      o[4] = (__bf16)b.x; o[5] = (__bf16)b.y; o[6] = (__bf16)b.z; o[7] = (__bf16)b.w;
      ((bf16x8*)out)[i] = o;
    }
  };
  conv(x, xb, (T * C) / 8);
  conv(Wa, Wab, (QKV_N * C) / 8);
  conv(Wp, Wpb, (C * C) / 8);
}

// ---------------------------------------------------------------- GEMM C = A * B^T + bias (+ fused RoPE)
// A: [M,K] bf16 row-major; B: [N,K] bf16 row-major; bias: [N] f32.
// 128x128 tile, BK=64, 4 waves in 2x2 of 64x64. Measured: 216us qkv, MfmaUtil 43,
// SQ_LDS_BANK_CONFLICT 0. (256^2 8-phase port tried rounds 1-3: 313us best — reverted.)
// ROPE=1 (qkv): head = 384 cols = 3 BN-blocks; blocks with blockIdx.x%3 in {0,1}
// hold rope dims 0..31 at wave-tile wn==0, cols nn*16+lr -> thread owns the
// (d, d+16) pair as acc[mm][0]/acc[mm][1]. Bias added BEFORE rotation (ref order).
template <int OUT_BF16, int ROPE>
__global__ __launch_bounds__(256, 2) void gemm_bt(const __bf16* __restrict__ A,
                                                  const __bf16* __restrict__ B,
                                                  const float* __restrict__ bias,
                                                  void* __restrict__ Cout,
                                                  const float* __restrict__ cosp,
                                                  const float* __restrict__ sinp,
                                                  int M, int N, int K) {
  constexpr int BM = 128, BN = 128, BK = 64;
  __shared__ __align__(16) __bf16 As[BM * BK]; // 16 KiB, swizzled 16B slots
  __shared__ __align__(16) __bf16 Bs[BN * BK];
  const int tid = threadIdx.x;
  const int lane = tid & 63;
  const int wid = tid >> 6;
  const int wm = (wid >> 1) * 64;
  const int wn = (wid & 1) * 64;
  const int m0 = blockIdx.y * BM;
  const int n0 = blockIdx.x * BN;
  const int lr = lane & 15;   // frag row (A) / col (B,C)
  const int quad = lane >> 4; // k-quad for inputs, row-quad for C

  fx4 acc[4][4] = {};

  for (int k0 = 0; k0 < K; k0 += BK) {
#pragma unroll
    for (int c = 0; c < 4; ++c) {
      int chunk = wid * 4 + c;
      int s = chunk * 64 + lane;
      int r = s >> 3;
      int kc = (s & 7) ^ (r & 7);
      async_cp16(A + (size_t)(m0 + r) * K + k0 + kc * 8, &As[chunk * 512]);
      async_cp16(B + (size_t)(n0 + r) * K + k0 + kc * 8, &Bs[chunk * 512]);
    }
    __syncthreads();
#pragma unroll
    for (int ks = 0; ks < BK; ks += 32) {
      bf16x8 af[4], bfr[4];
#pragma unroll
      for (int mm = 0; mm < 4; ++mm) {
        int r = wm + mm * 16 + lr;
        int kc = (ks >> 3) + quad;
        af[mm] = *(const bf16x8*)(&As[(r * 8 + (kc ^ (r & 7))) * 8]);
      }
#pragma unroll
      for (int nn = 0; nn < 4; ++nn) {
        int r = wn + nn * 16 + lr;
        int kc = (ks >> 3) + quad;
        bfr[nn] = *(const bf16x8*)(&Bs[(r * 8 + (kc ^ (r & 7))) * 8]);
      }
#pragma unroll
      for (int mm = 0; mm < 4; ++mm)
#pragma unroll
        for (int nn = 0; nn < 4; ++nn)
          acc[mm][nn] = MFMA16(af[mm], bfr[nn], acc[mm][nn]);
    }
    __syncthreads();
  }

  // bias first (reference applies rope AFTER x@W+b)
#pragma unroll
  for (int nn = 0; nn < 4; ++nn) {
    float bv = bias[n0 + wn + nn * 16 + lr];
#pragma unroll
    for (int mm = 0; mm < 4; ++mm)
#pragma unroll
      for (int r = 0; r < 4; ++r) acc[mm][nn][r] += bv;
  }

  // fused RoPE on q/k dims 0..31 (wave-uniform branch)
  if (ROPE && (blockIdx.x % 3) != 2 && wn == 0) {
#pragma unroll
    for (int mm = 0; mm < 4; ++mm) {
#pragma unroll
      for (int r = 0; r < 4; ++r) {
        int t = m0 + wm + mm * 16 + quad * 4 + r;
        float c1 = cosp[t * 32 + lr],      s1 = sinp[t * 32 + lr];
        float c2 = cosp[t * 32 + 16 + lr], s2 = sinp[t * 32 + 16 + lr];
        float x1 = acc[mm][0][r], x2 = acc[mm][1][r];
        acc[mm][0][r] = x1 * c1 - x2 * s1;
        acc[mm][1][r] = x2 * c2 + x1 * s2;
      }
    }
  }

  // C/D layout (m89/m91 verified): col = lane&15, row = (lane>>4)*4 + reg
#pragma unroll
  for (int nn = 0; nn < 4; ++nn) {
    int col = n0 + wn + nn * 16 + lr;
#pragma unroll
    for (int mm = 0; mm < 4; ++mm) {
#pragma unroll
      for (int r = 0; r < 4; ++r) {
        int row = m0 + wm + mm * 16 + quad * 4 + r;
        float v = acc[mm][nn][r];
        if (OUT_BF16)
          ((__bf16*)Cout)[(size_t)row * N + col] = (__bf16)v;
        else
          ((float*)Cout)[(size_t)row * N + col] = v;
      }
    }
  }
}

// ---------------------------------------------------------------- V transpose: vt[h][d][t] = v[h][t][d]
__global__ __launch_bounds__(256) void vtrans_kernel(const __bf16* __restrict__ qkv,
                                                     __bf16* __restrict__ vt) {
  __shared__ __align__(16) __bf16 tile[64][136];
  int h = blockIdx.x;
  int t0 = blockIdx.y * 64;
  int tid = threadIdx.x;
#pragma unroll
  for (int c = 0; c < 4; ++c) {
    int i = tid + c * 256;
    int tl = i >> 4;
    int dp = (i & 15) * 8;
    *(uint4*)(&tile[tl][dp]) = *(const uint4*)(qkv + (size_t)(t0 + tl) * QKV_N + h * 384 + 256 + dp);
  }
  __syncthreads();
#pragma unroll
  for (int c = 0; c < 4; ++c) {
    int o = tid + c * 256;   // 0..1023
    int d = o >> 3;          // 0..127
    int ts = (o & 7) * 8;    // t segment
    bf16x8 v;
#pragma unroll
    for (int j = 0; j < 8; ++j) v[j] = tile[ts + j][d];
    *(bf16x8*)(vt + ((size_t)h * 128 + d) * T + t0 + ts) = v;
  }
}

// ---------------------------------------------------------------- flash-style causal attention, NO-MAX softmax
// Round-4: double-buffered K/V staging, counted vmcnt(8) across raw s_barrier.
// Round-5: complementary-pair blocks (qb=pair and qb=31-pair) => 33 tile-units
// per block, 512 blocks = 512 resident slots, dispatch-order-independent balance.
__global__ __launch_bounds__(256, 2) void attn_kernel(const __bf16* __restrict__ qkv,
                                                      const __bf16* __restrict__ vt,
                                                      __bf16* __restrict__ y) {
  constexpr int KT = 64;
  constexpr int LPS = KT + 8; // 72
  __shared__ __align__(16) __bf16 Ks[2][KT * HS];  // 2 x 16 KiB swizzled
  __shared__ __align__(16) __bf16 Vs[2][HS * KT];  // 2 x 16 KiB swizzled
  __shared__ __align__(16) __bf16 Ps[4][16 * LPS];

  const int h = blockIdx.x;
  const int pairIdx = blockIdx.y; // 0..15
  const int tid = threadIdx.x;
  const int lane = tid & 63;
  const int wid = tid >> 6;
  const int lr = lane & 15;
  const int quad = lane >> 4;

  const float c_e2 = 0.08838834764831845f * 1.4426950408889634f; // scale*log2e

  for (int half = 0; half < 2; ++half) {
    const int qb = half ? (31 - pairIdx) : pairIdx;
    const int q0 = qb * 64;
    const int qrow = q0 + wid * 16;

    // Q A-frags in registers: A[m=lr][k=quad*8+j], 4 chunks over d=128
    bf16x8 qf[4];
#pragma unroll
    for (int kk = 0; kk < 4; ++kk)
      qf[kk] = *(const bf16x8*)(qkv + (size_t)(qrow + lr) * QKV_N + h * 384 + kk * 32 + quad * 8);

    float lsum[4];  // per-lane partial row sums (row = quad*4+r)
    fx4 acc_o[8];
#pragma unroll
    for (int r = 0; r < 4; ++r) lsum[r] = 0.f;
#pragma unroll
    for (int dd = 0; dd < 8; ++dd) acc_o[dd] = (fx4)0.f;

    const int ntiles = qb + 1;

    // 8 global_load_lds per thread per stage (4 K + 4 V)
    auto stage = [&](int kt, int buf) {
      const int kbase = kt * KT;
#pragma unroll
      for (int c = 0; c < 4; ++c) {
        int chunk = wid * 4 + c;
        int s = chunk * 64 + lane;
        int r = s >> 4;
        int kc = (s & 15) ^ (r & 15);
        async_cp16(qkv + (size_t)(kbase + r) * QKV_N + h * 384 + 128 + kc * 8,
                   &Ks[buf][chunk * 512]);
      }
#pragma unroll
      for (int c = 0; c < 4; ++c) {
        int chunk = wid * 4 + c;
        int s = chunk * 64 + lane;
        int r = s >> 3;
        int kc = (s & 7) ^ (r & 7);
        async_cp16(vt + ((size_t)h * 128 + r) * T + kbase + kc * 8,
                   &Vs[buf][chunk * 512]);
      }
    };

    auto compute = [&](int kt, int buf) {
      const int kbase = kt * KT;
      // S = Q K^T (16 x 64 per wave)
      fx4 sv[4] = {};
#pragma unroll
      for (int nn = 0; nn < 4; ++nn) {
#pragma unroll
        for (int kk = 0; kk < 4; ++kk) {
          int r = nn * 16 + lr;
          int kc = kk * 4 + quad;
          bf16x8 kf = *(const bf16x8*)(&Ks[buf][(r * 16 + (kc ^ (r & 15))) * 8]);
          sv[nn] = MFMA16(qf[kk], kf, sv[nn]);
        }
      }

      // p = exp2(s*c), masked to 0 beyond causal; per-lane row sums; P -> LDS (A-layout)
#pragma unroll
      for (int nn = 0; nn < 4; ++nn) {
        int kj = kbase + nn * 16 + lr;
#pragma unroll
        for (int r = 0; r < 4; ++r) {
          int qi = qrow + quad * 4 + r;
          float p = __builtin_amdgcn_exp2f(sv[nn][r] * c_e2); // v_exp_f32
          p = (kj > qi) ? 0.f : p;
          lsum[r] += p;
          Ps[wid][(quad * 4 + r) * LPS + nn * 16 + lr] = (__bf16)p;
        }
      }
      asm volatile("s_waitcnt lgkmcnt(0)" ::: "memory");

      // O += P @ V : A = P[m=qi][k=kj], B = Vs[n=d][k=kj]
#pragma unroll
      for (int kc0 = 0; kc0 < 2; ++kc0) {
        bf16x8 pf = *(const bf16x8*)(&Ps[wid][lr * LPS + kc0 * 32 + quad * 8]);
#pragma unroll
        for (int dd = 0; dd < 8; ++dd) {
          int r = dd * 16 + lr;
          int kc = kc0 * 4 + quad;
          bf16x8 vf = *(const bf16x8*)(&Vs[buf][(r * 8 + (kc ^ (r & 7))) * 8]);
          acc_o[dd] = MFMA16(pf, vf, acc_o[dd]);
        }
      }
    };

    // prologue
    stage(0, 0);
    int cur = 0;
    // steady state: prefetch t+1, counted-wait for t, compute t
    for (int kt = 0; kt < ntiles - 1; ++kt) {
      stage(kt + 1, cur ^ 1);
      asm volatile("s_waitcnt vmcnt(8)" ::: "memory"); // own 8 loads of buf[cur] done
      __builtin_amdgcn_sched_barrier(0);
      __builtin_amdgcn_s_barrier();                    // all waves' parts of buf[cur] visible
      __builtin_amdgcn_sched_barrier(0);
      compute(kt, cur);
      __builtin_amdgcn_sched_barrier(0);
      __builtin_amdgcn_s_barrier();                    // protect buf[cur] before restage next iter
      __builtin_amdgcn_sched_barrier(0);
      cur ^= 1;
    }
    // last tile: full drain
    asm volatile("s_waitcnt vmcnt(0)" ::: "memory");
    __builtin_amdgcn_sched_barrier(0);
    __builtin_amdgcn_s_barrier();
    __builtin_amdgcn_sched_barrier(0);
    compute(ntiles - 1, cur);

    // one reduction of row sums across the quad's 16 lanes
#pragma unroll
    for (int off = 1; off < 16; off <<= 1)
#pragma unroll
      for (int r = 0; r < 4; ++r)
        lsum[r] += __shfl_xor(lsum[r], off, 64);
#pragma unroll
    for (int r = 0; r < 4; ++r) lsum[r] = 1.0f / lsum[r];

#pragma unroll
    for (int dd = 0; dd < 8; ++dd)
#pragma unroll
      for (int r = 0; r < 4; ++r) {
        int row = qrow + quad * 4 + r;
        int col = h * 128 + dd * 16 + lr;
        y[(size_t)row * C + col] = (__bf16)(acc_o[dd][r] * lsum[r]);
      }

    // protect Ks/Vs/Ps before the second triangle reuses them
    __syncthreads();
  }
}

// ---------------------------------------------------------------- launcher
extern "C" void kernel_launch(void* const* d_in, const int* in_sizes, int n_in,
                              void* d_out, int out_size, void* d_ws, size_t ws_size,
                              hipStream_t stream) {
  const float* x      = (const float*)d_in[0];
  const float* cosp   = (const float*)d_in[1];
  const float* sinp   = (const float*)d_in[2];
  const float* W_attn = (const float*)d_in[3];
  const float* b_attn = (const float*)d_in[4];
  const float* W_proj = (const float*)d_in[5];
  const float* b_proj = (const float*)d_in[6];
  float* out = (float*)d_out;

  // workspace layout (bytes), all 16B aligned; total 234,881,024
  char* wsb = (char*)d_ws;
  __bf16* Wab  = (__bf16*)(wsb + 0);          // 12288*4096*2 = 100663296
  __bf16* Wpb  = (__bf16*)(wsb + 100663296);  // 4096*4096*2  =  33554432
  __bf16* xb   = (__bf16*)(wsb + 134217728);  // 2048*4096*2  =  16777216
  __bf16* qkvb = (__bf16*)(wsb + 150994944);  // 2048*12288*2 =  50331648
  __bf16* yb   = (__bf16*)(wsb + 201326592);  // 2048*4096*2  =  16777216
  __bf16* vtb  = (__bf16*)(wsb + 218103808);  // 32*128*2048*2=  16777216

  // one fused conversion pass (x, W_attn, W_proj)
  cvt_all<<<2048, 256, 0, stream>>>(x, W_attn, W_proj, xb, Wab, Wpb);

  // qkv = x @ W_attn^T + b_attn, RoPE fused in epilogue (M=2048, N=12288, K=4096)
  gemm_bt<1, 1><<<dim3(96, 16), 256, 0, stream>>>(xb, Wab, b_attn, (void*)qkvb,
                                                  cosp, sinp, T, QKV_N, C);

  vtrans_kernel<<<dim3(32, 32), 256, 0, stream>>>(qkvb, vtb);

  // 512 blocks = 512 resident slots (2/CU); each block does qb=pair and qb=31-pair
  attn_kernel<<<dim3(32, 16), 256, 0, stream>>>(qkvb, vtb, yb);

  // out = y @ W_proj^T + b_proj   (M=2048, N=4096, K=4096), fp32 out
  gemm_bt<0, 0><<<dim3(32, 16), 256, 0, stream>>>(yb, Wpb, b_proj, (void*)out,
                                                  nullptr, nullptr, T, C, C);
}

// Round 7
// 731.426 us; speedup vs baseline: 1.0254x; 1.0254x over previous
//
#include <hip/hip_runtime.h>
#include <cstdint>
#include <cstddef>

typedef __bf16 bf16x8 __attribute__((ext_vector_type(8)));
typedef __bf16 bf16x4 __attribute__((ext_vector_type(4)));
typedef float fx4 __attribute__((ext_vector_type(4)));

static constexpr int T = 2048;
static constexpr int C = 4096;
static constexpr int H = 32;
static constexpr int HS = 128;
static constexpr int QKV_N = 12288; // 3*C

#define MFMA16(a, b, c) __builtin_amdgcn_mfma_f32_16x16x32_bf16((a), (b), (c), 0, 0, 0)

// async global->LDS, 16B per lane. LDS dest = wave-uniform base + lane*16 (m97/m104).
__device__ __forceinline__ void async_cp16(const void* g, void* l) {
  __builtin_amdgcn_global_load_lds((const __attribute__((address_space(1))) unsigned int*)g,
                                   (__attribute__((address_space(3))) unsigned int*)l,
                                   16, 0, 0);
}

// ---------------------------------------------------------------- fp32 -> bf16
// (round-6 fused cvt_all was +27us SLOWER than these three — reverted)
__global__ __launch_bounds__(256) void cvt_f32_to_bf16(const float* __restrict__ in,
                                                       __bf16* __restrict__ out, int n4) {
  int i = blockIdx.x * 256 + threadIdx.x;
  if (i >= n4) return;
  float4 v = ((const float4*)in)[i];
  bf16x4 o;
  o.x = (__bf16)v.x; o.y = (__bf16)v.y; o.z = (__bf16)v.z; o.w = (__bf16)v.w;
  ((bf16x4*)out)[i] = o;
}

// ---------------------------------------------------------------- GEMM C = A * B^T + bias
// A: [M,K] bf16 row-major; B: [N,K] bf16 row-major; bias: [N] f32.
// 128x128 tile, BK=64, 4 waves in 2x2 of 64x64. Measured: 216us qkv, MfmaUtil 43,
// SQ_LDS_BANK_CONFLICT 0. (256^2 8-phase: rounds 1-3, reverted. RoPE epilogue
// fusion: round 6, +9.5us on qkv + doubled absmax — reverted.)
template <int OUT_BF16>
__global__ __launch_bounds__(256, 2) void gemm_bt(const __bf16* __restrict__ A,
                                                  const __bf16* __restrict__ B,
                                                  const float* __restrict__ bias,
                                                  void* __restrict__ Cout,
                                                  int M, int N, int K) {
  constexpr int BM = 128, BN = 128, BK = 64;
  __shared__ __align__(16) __bf16 As[BM * BK]; // 16 KiB, swizzled 16B slots
  __shared__ __align__(16) __bf16 Bs[BN * BK];
  const int tid = threadIdx.x;
  const int lane = tid & 63;
  const int wid = tid >> 6;
  const int wm = (wid >> 1) * 64;
  const int wn = (wid & 1) * 64;
  const int m0 = blockIdx.y * BM;
  const int n0 = blockIdx.x * BN;
  const int lr = lane & 15;   // frag row (A) / col (B,C)
  const int quad = lane >> 4; // k-quad for inputs, row-quad for C

  fx4 acc[4][4] = {};

  for (int k0 = 0; k0 < K; k0 += BK) {
#pragma unroll
    for (int c = 0; c < 4; ++c) {
      int chunk = wid * 4 + c;
      int s = chunk * 64 + lane;
      int r = s >> 3;
      int kc = (s & 7) ^ (r & 7);
      async_cp16(A + (size_t)(m0 + r) * K + k0 + kc * 8, &As[chunk * 512]);
      async_cp16(B + (size_t)(n0 + r) * K + k0 + kc * 8, &Bs[chunk * 512]);
    }
    __syncthreads();
#pragma unroll
    for (int ks = 0; ks < BK; ks += 32) {
      bf16x8 af[4], bfr[4];
#pragma unroll
      for (int mm = 0; mm < 4; ++mm) {
        int r = wm + mm * 16 + lr;
        int kc = (ks >> 3) + quad;
        af[mm] = *(const bf16x8*)(&As[(r * 8 + (kc ^ (r & 7))) * 8]);
      }
#pragma unroll
      for (int nn = 0; nn < 4; ++nn) {
        int r = wn + nn * 16 + lr;
        int kc = (ks >> 3) + quad;
        bfr[nn] = *(const bf16x8*)(&Bs[(r * 8 + (kc ^ (r & 7))) * 8]);
      }
#pragma unroll
      for (int mm = 0; mm < 4; ++mm)
#pragma unroll
        for (int nn = 0; nn < 4; ++nn)
          acc[mm][nn] = MFMA16(af[mm], bfr[nn], acc[mm][nn]);
    }
    __syncthreads();
  }

  // C/D layout (m89/m91 verified): col = lane&15, row = (lane>>4)*4 + reg
#pragma unroll
  for (int nn = 0; nn < 4; ++nn) {
    int col = n0 + wn + nn * 16 + lr;
    float bv = bias[col];
#pragma unroll
    for (int mm = 0; mm < 4; ++mm) {
#pragma unroll
      for (int r = 0; r < 4; ++r) {
        int row = m0 + wm + mm * 16 + quad * 4 + r;
        float v = acc[mm][nn][r] + bv;
        if (OUT_BF16)
          ((__bf16*)Cout)[(size_t)row * N + col] = (__bf16)v;
        else
          ((float*)Cout)[(size_t)row * N + col] = v;
      }
    }
  }
}

// ---------------------------------------------------------------- RoPE in-place on qkv (q and k, dims 0..31)
__global__ __launch_bounds__(256) void rope_kernel(__bf16* __restrict__ qkv,
                                                   const float* __restrict__ cosp,
                                                   const float* __restrict__ sinp) {
  int tid = blockIdx.x * 256 + threadIdx.x; // total 2048*32*2*16
  int d = tid & 15;
  int which = (tid >> 4) & 1;
  int h = (tid >> 5) & 31;
  int t = tid >> 10;
  size_t base = (size_t)t * QKV_N + h * 384 + which * 128;
  float x1 = (float)qkv[base + d];
  float x2 = (float)qkv[base + d + 16];
  float c1 = cosp[t * 32 + d], s1 = sinp[t * 32 + d];
  float c2 = cosp[t * 32 + d + 16], s2 = sinp[t * 32 + d + 16];
  qkv[base + d] = (__bf16)(x1 * c1 - x2 * s1);
  qkv[base + d + 16] = (__bf16)(x2 * c2 + x1 * s2);
}

// ---------------------------------------------------------------- V transpose: vt[h][d][t] = v[h][t][d]
__global__ __launch_bounds__(256) void vtrans_kernel(const __bf16* __restrict__ qkv,
                                                     __bf16* __restrict__ vt) {
  __shared__ __align__(16) __bf16 tile[64][136];
  int h = blockIdx.x;
  int t0 = blockIdx.y * 64;
  int tid = threadIdx.x;
#pragma unroll
  for (int c = 0; c < 4; ++c) {
    int i = tid + c * 256;
    int tl = i >> 4;
    int dp = (i & 15) * 8;
    *(uint4*)(&tile[tl][dp]) = *(const uint4*)(qkv + (size_t)(t0 + tl) * QKV_N + h * 384 + 256 + dp);
  }
  __syncthreads();
#pragma unroll
  for (int c = 0; c < 4; ++c) {
    int o = tid + c * 256;   // 0..1023
    int d = o >> 3;          // 0..127
    int ts = (o & 7) * 8;    // t segment
    bf16x8 v;
#pragma unroll
    for (int j = 0; j < 8; ++j) v[j] = tile[ts + j][d];
    *(bf16x8*)(vt + ((size_t)h * 128 + d) * T + t0 + ts) = v;
  }
}

// ---------------------------------------------------------------- flash-style causal attention, NO-MAX softmax
// Round-4: double-buffered K/V staging, counted vmcnt across raw s_barrier.
// Round-5: complementary-pair Q-blocks for causal balance.
// Round-7: 8 WAVES / 512 THREADS, 128 Q-rows per block. Theory: inner loop is
// LDS-read-bound (34 ds_read_b128 vs 32 MFMA per wave per tile); each staged
// 32KB K/V tile now serves 128 Q-rows instead of 64 -> LDS traffic per unit
// work HALVES. ntiles(qb)=2qb+2 (qb 0..15); pair (p, 15-p) = 34 tile-units per
// block; 256 blocks = 1/CU, 8 waves/CU (same wave count as 2x256 before).
// LDS: 2x16K (K) + 2x16K (V) + 8x2.3K (Ps) = 84KB -> 1 block/CU.
__global__ __launch_bounds__(512, 1) void attn_kernel(const __bf16* __restrict__ qkv,
                                                      const __bf16* __restrict__ vt,
                                                      __bf16* __restrict__ y) {
  constexpr int KT = 64;
  constexpr int LPS = KT + 8; // 72
  __shared__ __align__(16) __bf16 Ks[2][KT * HS];  // 2 x 16 KiB swizzled
  __shared__ __align__(16) __bf16 Vs[2][HS * KT];  // 2 x 16 KiB swizzled
  __shared__ __align__(16) __bf16 Ps[8][16 * LPS];

  const int h = blockIdx.x;
  const int pairIdx = blockIdx.y; // 0..7
  const int tid = threadIdx.x;
  const int lane = tid & 63;
  const int wid = tid >> 6;       // 0..7
  const int lr = lane & 15;
  const int quad = lane >> 4;

  const float c_e2 = 0.08838834764831845f * 1.4426950408889634f; // scale*log2e

  for (int half = 0; half < 2; ++half) {
    const int qb = half ? (15 - pairIdx) : pairIdx; // 0..15
    const int q0 = qb * 128;
    const int qrow = q0 + wid * 16;

    // Q A-frags in registers: A[m=lr][k=quad*8+j], 4 chunks over d=128
    bf16x8 qf[4];
#pragma unroll
    for (int kk = 0; kk < 4; ++kk)
      qf[kk] = *(const bf16x8*)(qkv + (size_t)(qrow + lr) * QKV_N + h * 384 + kk * 32 + quad * 8);

    float lsum[4];  // per-lane partial row sums (row = quad*4+r)
    fx4 acc_o[8];
#pragma unroll
    for (int r = 0; r < 4; ++r) lsum[r] = 0.f;
#pragma unroll
    for (int dd = 0; dd < 8; ++dd) acc_o[dd] = (fx4)0.f;

    const int ntiles = 2 * qb + 2; // K tiles covering rows <= q0+127

    // 4 global_load_lds per thread per stage (2 K + 2 V), 8 waves cover 16 chunks
    auto stage = [&](int kt, int buf) {
      const int kbase = kt * KT;
#pragma unroll
      for (int c = 0; c < 2; ++c) {
        int chunk = wid * 2 + c;
        int s = chunk * 64 + lane;
        int r = s >> 4;
        int kc = (s & 15) ^ (r & 15);
        async_cp16(qkv + (size_t)(kbase + r) * QKV_N + h * 384 + 128 + kc * 8,
                   &Ks[buf][chunk * 512]);
      }
#pragma unroll
      for (int c = 0; c < 2; ++c) {
        int chunk = wid * 2 + c;
        int s = chunk * 64 + lane;
        int r = s >> 3;
        int kc = (s & 7) ^ (r & 7);
        async_cp16(vt + ((size_t)h * 128 + r) * T + kbase + kc * 8,
                   &Vs[buf][chunk * 512]);
      }
    };

    auto compute = [&](int kt, int buf) {
      const int kbase = kt * KT;
      // S = Q K^T (16 x 64 per wave)
      fx4 sv[4] = {};
#pragma unroll
      for (int nn = 0; nn < 4; ++nn) {
#pragma unroll
        for (int kk = 0; kk < 4; ++kk) {
          int r = nn * 16 + lr;
          int kc = kk * 4 + quad;
          bf16x8 kf = *(const bf16x8*)(&Ks[buf][(r * 16 + (kc ^ (r & 15))) * 8]);
          sv[nn] = MFMA16(qf[kk], kf, sv[nn]);
        }
      }

      // p = exp2(s*c), masked to 0 beyond causal; per-lane row sums; P -> LDS (A-layout)
#pragma unroll
      for (int nn = 0; nn < 4; ++nn) {
        int kj = kbase + nn * 16 + lr;
#pragma unroll
        for (int r = 0; r < 4; ++r) {
          int qi = qrow + quad * 4 + r;
          float p = __builtin_amdgcn_exp2f(sv[nn][r] * c_e2); // v_exp_f32
          p = (kj > qi) ? 0.f : p;
          lsum[r] += p;
          Ps[wid][(quad * 4 + r) * LPS + nn * 16 + lr] = (__bf16)p;
        }
      }
      asm volatile("s_waitcnt lgkmcnt(0)" ::: "memory");

      // O += P @ V : A = P[m=qi][k=kj], B = Vs[n=d][k=kj]
#pragma unroll
      for (int kc0 = 0; kc0 < 2; ++kc0) {
        bf16x8 pf = *(const bf16x8*)(&Ps[wid][lr * LPS + kc0 * 32 + quad * 8]);
#pragma unroll
        for (int dd = 0; dd < 8; ++dd) {
          int r = dd * 16 + lr;
          int kc = kc0 * 4 + quad;
          bf16x8 vf = *(const bf16x8*)(&Vs[buf][(r * 8 + (kc ^ (r & 7))) * 8]);
          acc_o[dd] = MFMA16(pf, vf, acc_o[dd]);
        }
      }
    };

    // prologue
    stage(0, 0);
    int cur = 0;
    // steady state: prefetch t+1, counted-wait for t, compute t
    for (int kt = 0; kt < ntiles - 1; ++kt) {
      stage(kt + 1, cur ^ 1);
      asm volatile("s_waitcnt vmcnt(4)" ::: "memory"); // own 4 loads of buf[cur] done
      __builtin_amdgcn_sched_barrier(0);
      __builtin_amdgcn_s_barrier();                    // all waves' parts of buf[cur] visible
      __builtin_amdgcn_sched_barrier(0);
      compute(kt, cur);
      __builtin_amdgcn_sched_barrier(0);
      __builtin_amdgcn_s_barrier();                    // protect buf[cur] before restage next iter
      __builtin_amdgcn_sched_barrier(0);
      cur ^= 1;
    }
    // last tile: full drain
    asm volatile("s_waitcnt vmcnt(0)" ::: "memory");
    __builtin_amdgcn_sched_barrier(0);
    __builtin_amdgcn_s_barrier();
    __builtin_amdgcn_sched_barrier(0);
    compute(ntiles - 1, cur);

    // one reduction of row sums across the quad's 16 lanes
#pragma unroll
    for (int off = 1; off < 16; off <<= 1)
#pragma unroll
      for (int r = 0; r < 4; ++r)
        lsum[r] += __shfl_xor(lsum[r], off, 64);
#pragma unroll
    for (int r = 0; r < 4; ++r) lsum[r] = 1.0f / lsum[r];

#pragma unroll
    for (int dd = 0; dd < 8; ++dd)
#pragma unroll
      for (int r = 0; r < 4; ++r) {
        int row = qrow + quad * 4 + r;
        int col = h * 128 + dd * 16 + lr;
        y[(size_t)row * C + col] = (__bf16)(acc_o[dd][r] * lsum[r]);
      }

    // protect Ks/Vs/Ps before the second triangle reuses them
    __syncthreads();
  }
}

// ---------------------------------------------------------------- launcher
extern "C" void kernel_launch(void* const* d_in, const int* in_sizes, int n_in,
                              void* d_out, int out_size, void* d_ws, size_t ws_size,
                              hipStream_t stream) {
  const float* x      = (const float*)d_in[0];
  const float* cosp   = (const float*)d_in[1];
  const float* sinp   = (const float*)d_in[2];
  const float* W_attn = (const float*)d_in[3];
  const float* b_attn = (const float*)d_in[4];
  const float* W_proj = (const float*)d_in[5];
  const float* b_proj = (const float*)d_in[6];
  float* out = (float*)d_out;

  // workspace layout (bytes), all 16B aligned; total 234,881,024
  char* wsb = (char*)d_ws;
  __bf16* Wab  = (__bf16*)(wsb + 0);          // 12288*4096*2 = 100663296
  __bf16* Wpb  = (__bf16*)(wsb + 100663296);  // 4096*4096*2  =  33554432
  __bf16* xb   = (__bf16*)(wsb + 134217728);  // 2048*4096*2  =  16777216
  __bf16* qkvb = (__bf16*)(wsb + 150994944);  // 2048*12288*2 =  50331648
  __bf16* yb   = (__bf16*)(wsb + 201326592);  // 2048*4096*2  =  16777216
  __bf16* vtb  = (__bf16*)(wsb + 218103808);  // 32*128*2048*2=  16777216

  cvt_f32_to_bf16<<<8192, 256, 0, stream>>>(x, xb, (T * C) / 4);
  cvt_f32_to_bf16<<<49152, 256, 0, stream>>>(W_attn, Wab, (QKV_N * C) / 4);
  cvt_f32_to_bf16<<<16384, 256, 0, stream>>>(W_proj, Wpb, (C * C) / 4);

  // qkv = x @ W_attn^T + b_attn   (M=2048, N=12288, K=4096)
  gemm_bt<1><<<dim3(96, 16), 256, 0, stream>>>(xb, Wab, b_attn, (void*)qkvb, T, QKV_N, C);

  rope_kernel<<<8192, 256, 0, stream>>>(qkvb, cosp, sinp);
  vtrans_kernel<<<dim3(32, 32), 256, 0, stream>>>(qkvb, vtb);

  // 256 blocks = 1/CU, 8 waves each; block does qb=pair and qb=15-pair (34 tile-units)
  attn_kernel<<<dim3(32, 8), 512, 0, stream>>>(qkvb, vtb, yb);

  // out = y @ W_proj^T + b_proj   (M=2048, N=4096, K=4096), fp32 out
  gemm_bt<0><<<dim3(32, 16), 256, 0, stream>>>(yb, Wpb, b_proj, (void*)out, T, C, C);
}